// Round 6
// baseline (1587.194 us; speedup 1.0000x reference)
//
#include <hip/hip_runtime.h>
#include <hip/hip_bf16.h>

#define B_   64
#define T_   2048
#define IN_  256
#define H_   128
#define G_   512          // 4*H
#define M_   (B_ * T_)    // 131072

typedef _Float16 half2v __attribute__((ext_vector_type(2)));
typedef __bf16 bf16x8 __attribute__((ext_vector_type(8)));
typedef float f32x4 __attribute__((ext_vector_type(4)));
typedef unsigned short u16x8 __attribute__((ext_vector_type(8)));

#define L2E_  1.442695041f

__device__ __forceinline__ float dot2f(half2v a, half2v b, float c) {
    return __builtin_amdgcn_fdot2(a, b, c, false);
}
__device__ __forceinline__ half2v mk2(float a, float b) {
    half2v h; h.x = (_Float16)a; h.y = (_Float16)b; return h;
}
__device__ __forceinline__ unsigned short f2bf(float f) {   // RNE fp32->bf16
    unsigned u = __float_as_uint(f);
    return (unsigned short)((u + 0x7fffu + ((u >> 16) & 1u)) >> 16);
}
__device__ __forceinline__ float dpp_xor1(float x) {
    int i = __float_as_int(x);
    return __int_as_float(__builtin_amdgcn_update_dpp(i, i, 0xB1, 0xF, 0xF, true));
}
__device__ __forceinline__ float dpp_xor2(float x) {
    int i = __float_as_int(x);
    return __int_as_float(__builtin_amdgcn_update_dpp(i, i, 0x4E, 0xF, 0xF, true));
}
__device__ __forceinline__ float tanhp(float x) {
    return fmaf(2.f, __builtin_amdgcn_rcpf(1.f + __builtin_amdgcn_exp2f(-2.f * L2E_ * x)), -1.f);
}

// ---------------------------------------------------------------------------
// K1: bf16 MFMA GEMM.  xp[dir][m][q*4+g] = x[m].w_ih[dir][g*128+q] + biases
// ---------------------------------------------------------------------------
__global__ __launch_bounds__(256) void gemm_in_mfma(
    const float* __restrict__ x,
    const float* __restrict__ w_f, const float* __restrict__ w_b,
    const float* __restrict__ bi_f, const float* __restrict__ bh_f,
    const float* __restrict__ bi_b, const float* __restrict__ bh_b,
    __hip_bfloat16* __restrict__ xp)
{
    const int nt  = blockIdx.x;          // 0..15
    const int m0  = blockIdx.y * 64;
    const int dir = nt >> 3;
    const int q0  = (nt & 7) * 16;
    const float* __restrict__ w  = dir ? w_b  : w_f;
    const float* __restrict__ bi = dir ? bi_b : bi_f;
    const float* __restrict__ bh = dir ? bh_b : bh_f;

    __shared__ alignas(16) unsigned short Asm[64 * 64];
    __shared__ alignas(16) unsigned short Bsm[64 * 64];
    __shared__ float bias_s[64];

    const int tid = threadIdx.x;
    const int wv  = tid >> 6;
    const int ln  = tid & 63;
    const int wr  = (wv >> 1) * 32;
    const int wc  = (wv & 1) * 32;
    const int l15 = ln & 15;
    const int l4  = ln >> 4;

#define STAGE_A(c2, k0) { int row = (c2) >> 3, kc = (c2) & 7; \
    const float4* sp = reinterpret_cast<const float4*>(x + (size_t)(m0 + row) * 256 + (k0) + kc * 8); \
    float4 fa = sp[0], fb = sp[1]; \
    u16x8 pk; pk[0]=f2bf(fa.x); pk[1]=f2bf(fa.y); pk[2]=f2bf(fa.z); pk[3]=f2bf(fa.w); \
    pk[4]=f2bf(fb.x); pk[5]=f2bf(fb.y); pk[6]=f2bf(fb.z); pk[7]=f2bf(fb.w); \
    *reinterpret_cast<u16x8*>(reinterpret_cast<char*>(Asm) + row * 128 + ((kc * 16) ^ ((row & 7) << 4))) = pk; }

#define STAGE_B(c2, k0) { int row = (c2) >> 3, kc = (c2) & 7; \
    int nglob = (row & 3) * 128 + q0 + (row >> 2); \
    const float4* sp = reinterpret_cast<const float4*>(w + (size_t)nglob * 256 + (k0) + kc * 8); \
    float4 fa = sp[0], fb = sp[1]; \
    u16x8 pk; pk[0]=f2bf(fa.x); pk[1]=f2bf(fa.y); pk[2]=f2bf(fa.z); pk[3]=f2bf(fa.w); \
    pk[4]=f2bf(fb.x); pk[5]=f2bf(fb.y); pk[6]=f2bf(fb.z); pk[7]=f2bf(fb.w); \
    *reinterpret_cast<u16x8*>(reinterpret_cast<char*>(Bsm) + row * 128 + ((kc * 16) ^ ((row & 7) << 4))) = pk; }

#define FRAG(BASE, rowe, kb) \
    __builtin_bit_cast(bf16x8, *reinterpret_cast<const uint4*>( \
        reinterpret_cast<const char*>(BASE) + (rowe) * 128 + ((kb) ^ (((rowe) & 7) << 4))))

    STAGE_A(tid, 0)  STAGE_A(tid + 256, 0)
    STAGE_B(tid, 0)  STAGE_B(tid + 256, 0)
    if (tid < 64) {
        int n = (tid & 3) * 128 + q0 + (tid >> 2);
        bias_s[tid] = bi[n] + bh[n];
    }
    __syncthreads();

    const float bv0 = bias_s[wc + l15];
    const float bv1 = bias_s[wc + 16 + l15];
    f32x4 acc00 = {bv0, bv0, bv0, bv0};
    f32x4 acc01 = {bv1, bv1, bv1, bv1};
    f32x4 acc10 = {bv0, bv0, bv0, bv0};
    f32x4 acc11 = {bv1, bv1, bv1, bv1};

    const int ra0 = wr + l15,      ra1 = wr + 16 + l15;
    const int rb0 = wc + l15,      rb1 = wc + 16 + l15;

    for (int kst = 0; kst < 4; ++kst) {
        if (kst) {
            __syncthreads();
            STAGE_A(tid, kst * 64)  STAGE_A(tid + 256, kst * 64)
            STAGE_B(tid, kst * 64)  STAGE_B(tid + 256, kst * 64)
            __syncthreads();
        }
        #pragma unroll
        for (int ks = 0; ks < 64; ks += 32) {
            int kb = ks * 2 + (l4 << 4);
            bf16x8 a0 = FRAG(Asm, ra0, kb);
            bf16x8 a1 = FRAG(Asm, ra1, kb);
            bf16x8 b0 = FRAG(Bsm, rb0, kb);
            bf16x8 b1 = FRAG(Bsm, rb1, kb);
            acc00 = __builtin_amdgcn_mfma_f32_16x16x32_bf16(a0, b0, acc00, 0, 0, 0);
            acc01 = __builtin_amdgcn_mfma_f32_16x16x32_bf16(a0, b1, acc01, 0, 0, 0);
            acc10 = __builtin_amdgcn_mfma_f32_16x16x32_bf16(a1, b0, acc10, 0, 0, 0);
            acc11 = __builtin_amdgcn_mfma_f32_16x16x32_bf16(a1, b1, acc11, 0, 0, 0);
        }
    }
    __syncthreads();

#define DWRITE(accv, mi, ni) { int row = wr + (mi) * 16 + l4 * 4; int col = wc + (ni) * 16 + l15; \
    Asm[(row + 0) * 64 + col] = f2bf(accv[0]); Asm[(row + 1) * 64 + col] = f2bf(accv[1]); \
    Asm[(row + 2) * 64 + col] = f2bf(accv[2]); Asm[(row + 3) * 64 + col] = f2bf(accv[3]); }
    DWRITE(acc00, 0, 0) DWRITE(acc01, 0, 1) DWRITE(acc10, 1, 0) DWRITE(acc11, 1, 1)
#undef DWRITE
    __syncthreads();

    #pragma unroll
    for (int p = 0; p < 2; ++p) {
        int c2 = tid + p * 256;
        int row = c2 >> 3, ch = c2 & 7;
        uint4 v = *reinterpret_cast<const uint4*>(reinterpret_cast<const char*>(Asm) + row * 128 + ch * 16);
        *reinterpret_cast<uint4*>(xp + ((size_t)dir * M_ + m0 + row) * G_ + q0 * 4 + ch * 8) = v;
    }
#undef STAGE_A
#undef STAGE_B
}

// ---------------------------------------------------------------------------
// K2: persistent recurrence, own-gate full-K layout. 128 WGs=(dir,b); 512 thr.
// tid = Q*4 + g: lane computes gate g of cell Q over FULL K=128 (64 dot2,
// 4 accumulators). No K-partial butterfly. h read = 16 broadcast b128.
// Own activation only (1 exp2+1 rcp); 3 DPP exchange; redundant c-update.
// ---------------------------------------------------------------------------
__global__ __launch_bounds__(512, 2) void lstm_rec(
    const __hip_bfloat16* __restrict__ xp,   // [2][B][T][128][4]
    const float* __restrict__ w_hh_f,        // [G][H]
    const float* __restrict__ w_hh_b,
    __hip_bfloat16* __restrict__ hs)         // [B][T][2H]
{
    const int wg  = blockIdx.x;
    const int dir = wg >> 6;
    const int b   = wg & 63;
    const int tid = threadIdx.x;
    const int g   = tid & 3;
    const int Q   = tid >> 2;
    const float* __restrict__ w_hh = dir ? w_hh_b : w_hh_f;
    const float* __restrict__ wrow = w_hh + (size_t)(g * H_ + Q) * H_;

    // full W row (128 fp16 = 64 half2) in named registers
#define LWC(c) half2v W##c##_0,W##c##_1,W##c##_2,W##c##_3,W##c##_4,W##c##_5,W##c##_6,W##c##_7; { \
    const float4* p = reinterpret_cast<const float4*>(wrow + (c) * 16); \
    float4 r0 = p[0], r1 = p[1], r2 = p[2], r3 = p[3]; \
    W##c##_0 = mk2(r0.x, r0.y); W##c##_1 = mk2(r0.z, r0.w); \
    W##c##_2 = mk2(r1.x, r1.y); W##c##_3 = mk2(r1.z, r1.w); \
    W##c##_4 = mk2(r2.x, r2.y); W##c##_5 = mk2(r2.z, r2.w); \
    W##c##_6 = mk2(r3.x, r3.y); W##c##_7 = mk2(r3.z, r3.w); }
    LWC(0) LWC(1) LWC(2) LWC(3) LWC(4) LWC(5) LWC(6) LWC(7)
#undef LWC

    __shared__ alignas(16) _Float16 hbuf[2][H_];
    if (tid < 2 * H_) (&hbuf[0][0])[tid] = (_Float16)0.f;
    float c = 0.f;
    __syncthreads();

    const unsigned short* __restrict__ xb =
        reinterpret_cast<const unsigned short*>(xp) + ((size_t)(dir * B_ + b)) * T_ * G_;
    __hip_bfloat16* __restrict__ ho =
        hs + (size_t)b * T_ * (2 * H_) + dir * H_ + Q;

    int t = dir ? (T_ - 1) : 0;
    const int dt = dir ? -1 : 1;
    const float kk = (g == 2) ? (-2.f * L2E_) : (-L2E_);

#define XPLD(sp) ((unsigned int)xb[(size_t)(dir ? (T_ - 1 - (sp)) : (sp)) * G_ + tid])
    unsigned int cur0 = XPLD(0), cur1 = XPLD(1), cur2 = XPLD(2), cur3 = XPLD(3);

#define DOTC(c, HA, HB, P) { \
    P = dot2f(W##c##_0, __builtin_bit_cast(half2v, HA.x), P); \
    P = dot2f(W##c##_1, __builtin_bit_cast(half2v, HA.y), P); \
    P = dot2f(W##c##_2, __builtin_bit_cast(half2v, HA.z), P); \
    P = dot2f(W##c##_3, __builtin_bit_cast(half2v, HA.w), P); \
    P = dot2f(W##c##_4, __builtin_bit_cast(half2v, HB.x), P); \
    P = dot2f(W##c##_5, __builtin_bit_cast(half2v, HB.y), P); \
    P = dot2f(W##c##_6, __builtin_bit_cast(half2v, HB.z), P); \
    P = dot2f(W##c##_7, __builtin_bit_cast(half2v, HB.w), P); }

#define STEP(par, CUR) { \
    const uint4* hv = reinterpret_cast<const uint4*>(hbuf[par]); \
    uint4 h0 = hv[0],  h1 = hv[1],  h2 = hv[2],  h3 = hv[3]; \
    uint4 h4 = hv[4],  h5 = hv[5],  h6 = hv[6],  h7 = hv[7]; \
    uint4 h8 = hv[8],  h9 = hv[9],  h10 = hv[10], h11 = hv[11]; \
    uint4 h12 = hv[12], h13 = hv[13], h14 = hv[14], h15 = hv[15]; \
    float pa = __uint_as_float(CUR << 16), pb = 0.f, pc = 0.f, pd = 0.f; \
    DOTC(0, h0,  h1,  pa)  DOTC(1, h2,  h3,  pb) \
    DOTC(2, h4,  h5,  pc)  DOTC(3, h6,  h7,  pd) \
    DOTC(4, h8,  h9,  pa)  DOTC(5, h10, h11, pb) \
    DOTC(6, h12, h13, pc)  DOTC(7, h14, h15, pd) \
    float pre = (pa + pb) + (pc + pd); \
    float y   = __builtin_amdgcn_rcpf(1.f + __builtin_amdgcn_exp2f(kk * pre)); \
    float act = (g == 2) ? fmaf(2.f, y, -1.f) : y; \
    float e1 = dpp_xor1(act); \
    float e2 = dpp_xor2(act); \
    float e3 = dpp_xor1(e2); \
    float si = (g==0)?act:(g==1)?e1:(g==2)?e2:e3; \
    float sf = (g==1)?act:(g==0)?e1:(g==3)?e2:e3; \
    float tg = (g==2)?act:(g==3)?e1:(g==0)?e2:e3; \
    float so = (g==3)?act:(g==2)?e1:(g==1)?e2:e3; \
    c = fmaf(sf, c, si * tg); \
    float h = so * tanhp(c); \
    if (g == 0) { \
        hbuf[(par) ^ 1][Q] = (_Float16)h; \
        ho[(size_t)t * (2 * H_)] = __float2bfloat16(h); \
    } \
    asm volatile("s_waitcnt lgkmcnt(0)" ::: "memory"); \
    __builtin_amdgcn_s_barrier(); \
    t += dt; }

    for (int blk = 0; blk < T_ / 4; ++blk) {
        int base = blk * 4 + 4;
        int s0 = base     > T_ - 1 ? T_ - 1 : base;
        int s1 = base + 1 > T_ - 1 ? T_ - 1 : base + 1;
        int s2 = base + 2 > T_ - 1 ? T_ - 1 : base + 2;
        int s3 = base + 3 > T_ - 1 ? T_ - 1 : base + 3;
        unsigned int nxt0 = XPLD(s0), nxt1 = XPLD(s1), nxt2 = XPLD(s2), nxt3 = XPLD(s3);

        STEP(0, cur0)
        STEP(1, cur1)
        STEP(0, cur2)
        STEP(1, cur3)

        cur0 = nxt0; cur1 = nxt1; cur2 = nxt2; cur3 = nxt3;
    }
#undef STEP
#undef DOTC
#undef XPLD
}

// ---------------------------------------------------------------------------
// K3: bf16 MFMA mixer. out[m][n] = hs[m].mixer_w[n] + mb[n], fp32 out.
// ---------------------------------------------------------------------------
__global__ __launch_bounds__(256) void mixer_mfma(
    const __hip_bfloat16* __restrict__ hs,   // [M][256] bf16
    const float* __restrict__ mw,            // [256][256] fp32
    const float* __restrict__ mb,
    float* __restrict__ out)                 // [M][256] fp32
{
    const int n0 = blockIdx.x * 64;
    const int m0 = blockIdx.y * 64;

    __shared__ alignas(16) unsigned short Asm[64 * 64];
    __shared__ alignas(16) unsigned short Bsm[64 * 64];
    __shared__ alignas(16) float Dlds[64 * 64];
    __shared__ float bias_s[64];

    const int tid = threadIdx.x;
    const int wv  = tid >> 6;
    const int ln  = tid & 63;
    const int wr  = (wv >> 1) * 32;
    const int wc  = (wv & 1) * 32;
    const int l15 = ln & 15;
    const int l4  = ln >> 4;

#define STAGE_A3(c2, k0) { int row = (c2) >> 3, kc = (c2) & 7; \
    uint4 v = *reinterpret_cast<const uint4*>(hs + (size_t)(m0 + row) * 256 + (k0) + kc * 8); \
    *reinterpret_cast<uint4*>(reinterpret_cast<char*>(Asm) + row * 128 + ((kc * 16) ^ ((row & 7) << 4))) = v; }
#define STAGE_B3(c2, k0) { int row = (c2) >> 3, kc = (c2) & 7; \
    const float4* sp = reinterpret_cast<const float4*>(mw + (size_t)(n0 + row) * 256 + (k0) + kc * 8); \
    float4 fa = sp[0], fb = sp[1]; \
    u16x8 pk; pk[0]=f2bf(fa.x); pk[1]=f2bf(fa.y); pk[2]=f2bf(fa.z); pk[3]=f2bf(fa.w); \
    pk[4]=f2bf(fb.x); pk[5]=f2bf(fb.y); pk[6]=f2bf(fb.z); pk[7]=f2bf(fb.w); \
    *reinterpret_cast<u16x8*>(reinterpret_cast<char*>(Bsm) + row * 128 + ((kc * 16) ^ ((row & 7) << 4))) = pk; }

    STAGE_A3(tid, 0)  STAGE_A3(tid + 256, 0)
    STAGE_B3(tid, 0)  STAGE_B3(tid + 256, 0)
    if (tid < 64) bias_s[tid] = mb[n0 + tid];
    __syncthreads();

    const float bv0 = bias_s[wc + l15];
    const float bv1 = bias_s[wc + 16 + l15];
    f32x4 acc00 = {bv0, bv0, bv0, bv0};
    f32x4 acc01 = {bv1, bv1, bv1, bv1};
    f32x4 acc10 = {bv0, bv0, bv0, bv0};
    f32x4 acc11 = {bv1, bv1, bv1, bv1};

    const int ra0 = wr + l15,      ra1 = wr + 16 + l15;
    const int rb0 = wc + l15,      rb1 = wc + 16 + l15;

    for (int kst = 0; kst < 4; ++kst) {
        if (kst) {
            __syncthreads();
            STAGE_A3(tid, kst * 64)  STAGE_A3(tid + 256, kst * 64)
            STAGE_B3(tid, kst * 64)  STAGE_B3(tid + 256, kst * 64)
            __syncthreads();
        }
        #pragma unroll
        for (int ks = 0; ks < 64; ks += 32) {
            int kb = ks * 2 + (l4 << 4);
            bf16x8 a0 = FRAG(Asm, ra0, kb);
            bf16x8 a1 = FRAG(Asm, ra1, kb);
            bf16x8 b0 = FRAG(Bsm, rb0, kb);
            bf16x8 b1 = FRAG(Bsm, rb1, kb);
            acc00 = __builtin_amdgcn_mfma_f32_16x16x32_bf16(a0, b0, acc00, 0, 0, 0);
            acc01 = __builtin_amdgcn_mfma_f32_16x16x32_bf16(a0, b1, acc01, 0, 0, 0);
            acc10 = __builtin_amdgcn_mfma_f32_16x16x32_bf16(a1, b0, acc10, 0, 0, 0);
            acc11 = __builtin_amdgcn_mfma_f32_16x16x32_bf16(a1, b1, acc11, 0, 0, 0);
        }
    }
    __syncthreads();

#define DWRITE3(accv, mi, ni) { int row = wr + (mi) * 16 + l4 * 4; int col = wc + (ni) * 16 + l15; \
    Dlds[(row + 0) * 64 + col] = accv[0]; Dlds[(row + 1) * 64 + col] = accv[1]; \
    Dlds[(row + 2) * 64 + col] = accv[2]; Dlds[(row + 3) * 64 + col] = accv[3]; }
    DWRITE3(acc00, 0, 0) DWRITE3(acc01, 0, 1) DWRITE3(acc10, 1, 0) DWRITE3(acc11, 1, 1)
#undef DWRITE3
    __syncthreads();

    #pragma unroll
    for (int p = 0; p < 4; ++p) {
        int c2 = tid + p * 256;
        int row = c2 >> 4, ch = c2 & 15;
        float4 v = *reinterpret_cast<const float4*>(Dlds + row * 64 + ch * 4);
        *reinterpret_cast<float4*>(out + (size_t)(m0 + row) * 256 + n0 + ch * 4) = v;
    }
#undef STAGE_A3
#undef STAGE_B3
#undef FRAG
}

// ---------------------------------------------------------------------------
extern "C" void kernel_launch(void* const* d_in, const int* in_sizes, int n_in,
                              void* d_out, int out_size, void* d_ws, size_t ws_size,
                              hipStream_t stream) {
    const float* x       = (const float*)d_in[0];
    const float* w_ih_f  = (const float*)d_in[1];
    const float* w_hh_f  = (const float*)d_in[2];
    const float* b_ih_f  = (const float*)d_in[3];
    const float* b_hh_f  = (const float*)d_in[4];
    const float* w_ih_b  = (const float*)d_in[5];
    const float* w_hh_b  = (const float*)d_in[6];
    const float* b_ih_b  = (const float*)d_in[7];
    const float* b_hh_b  = (const float*)d_in[8];
    const float* mixer_w = (const float*)d_in[9];
    const float* mixer_b = (const float*)d_in[10];
    float* out = (float*)d_out;

    const size_t xp_bytes = (size_t)2 * M_ * G_ * sizeof(__hip_bfloat16); // 256 MiB
    const size_t hs_bytes = (size_t)M_ * 2 * H_ * sizeof(__hip_bfloat16); //  64 MiB
    if (ws_size < xp_bytes + hs_bytes) return;

    __hip_bfloat16* xp = (__hip_bfloat16*)d_ws;
    __hip_bfloat16* hs = (__hip_bfloat16*)((char*)d_ws + xp_bytes);

    gemm_in_mfma<<<dim3(16, M_ / 64), 256, 0, stream>>>(
        x, w_ih_f, w_ih_b, b_ih_f, b_hh_f, b_ih_b, b_hh_b, xp);
    lstm_rec<<<128, 512, 0, stream>>>(xp, w_hh_f, w_hh_b, hs);
    mixer_mfma<<<dim3(4, M_ / 64), 256, 0, stream>>>(
        hs, mixer_w, mixer_b, out);
}